// Round 4
// baseline (59574.701 us; speedup 1.0000x reference)
//
#include <hip/hip_runtime.h>
#include <hip/hip_cooperative_groups.h>
#include <stdint.h>

namespace cg = cooperative_groups;

#define N_NEUR  1024
#define N_INP   256
#define N_OUTC  32
#define T_STEPS 500
#define BATCH   64
#define N_DEL   8
#define NB      (N_NEUR*BATCH)     // 65536, layout [n][b], b fastest
#define HSLOTS  132                // ring: live window is 131 steps (writes t0,t0+1;
                                   // reads t0-129..t0-1) -> 132 proves no aliasing.
                                   // 130 RACED (slot(s-129)==slot(s+1)) - round 8 bug.
#define CAP     256                // per-(o,d) record capacity (mean 128, 12 sigma)
#define H1RING  64                 // h1 ring depth (steps), power of 2
#define LREC_MAX 1152              // >= 1024 + 8*3 padding

// ---------------------------------------------------------------------------
// inpT[t][c][b] = inputs[b][t][c]
__global__ __launch_bounds__(256) void transpose_inp(const float* __restrict__ inp,
                                                     float* __restrict__ inpT) {
    __shared__ float L[N_INP * 64];
    int t = blockIdx.x;
    int tid = threadIdx.x;                   // = c
    for (int b = 0; b < 64; ++b) {
        float v = inp[((size_t)b * T_STEPS + t) * N_INP + tid];
        L[tid * 64 + (b ^ (tid & 63))] = v;
    }
    __syncthreads();
    int lane = tid & 63;
    int wv   = tid >> 6;
    for (int cc = 0; cc < 64; ++cc) {
        int c = cc * 4 + wv;
        inpT[((size_t)t * N_INP + c) * 64 + lane] = L[c * 64 + (lane ^ (c & 63))];
    }
}

// w_inT[n][c] = w_in[c][n]
__global__ __launch_bounds__(256) void transpose_win(const float* __restrict__ w_in,
                                                     float* __restrict__ w_inT) {
    int i = blockIdx.x * 256 + threadIdx.x;  // 262144
    int n = i >> 8, c = i & 255;
    w_inT[i] = w_in[(size_t)c * N_NEUR + n];
}

// ---------------------------------------------------------------------------
// CSR build: for each (o,d), list of {G = sign[e]*|w[e][o]|, e*64} where
// dmap[d][e][o] == 1. Padded to a multiple of 4 with zero-records (G=0 -> inert).
// NOTE: records are e-ASCENDING within each (o,d) segment (load-bearing for
// bit-exact summation order).
__global__ __launch_bounds__(64) void build_csr(const float* __restrict__ w,
                                                const float* __restrict__ signs,
                                                const float* __restrict__ dmap,
                                                uint2* __restrict__ recs,
                                                int* __restrict__ cnt) {
    int o = blockIdx.x * 64 + threadIdx.x;   // 16 blocks x 64 lanes
    for (int d = 0; d < N_DEL; ++d) {
        int c = 0;
        uint2* seg = recs + ((size_t)o * N_DEL + d) * CAP;
        for (int e = 0; e < N_NEUR; ++e) {
            float m = dmap[((size_t)d * N_NEUR + e) * N_NEUR + o];  // coalesced over o
            if (m != 0.f) {
                float G = signs[e] * fabsf(w[(size_t)e * N_NEUR + o]);
                if (c < CAP) seg[c] = make_uint2(__float_as_uint(G), (unsigned)(e * 64));
                ++c;
            }
        }
        if (c > CAP) c = CAP;
        int c4 = (c + 3) & ~3;                // pad to multiple of 4
        for (; c < c4; ++c) seg[c] = make_uint2(0u, 0u);
        cnt[o * N_DEL + d] = c4;
    }
}

// ---------------------------------------------------------------------------
// h1 ring precompute, 64 steps per launch (bit-exact vs the round-7 in-step
// code: same per-wave c-split, same fma order, same 4-partial reduce).
__global__ __launch_bounds__(256) void h1_chunk(int t0,
        const float* __restrict__ inpT, const float* __restrict__ w_inT,
        float* __restrict__ h1r) {
    __shared__ float Li[N_INP * 64];   // 64 KB
    __shared__ float Lp[4 * 64];
    int s     = t0 + blockIdx.x;
    int ntile = blockIdx.y;            // 16 tiles x 64 n
    int tid   = threadIdx.x;
    int lane  = tid & 63;
    int wv    = tid >> 6;
    const float4* src = (const float4*)(inpT + (size_t)s * (N_INP * 64));
    float4* dst = (float4*)Li;
    for (int k = tid; k < (N_INP * 64) / 4; k += 256) dst[k] = src[k];
    __syncthreads();
    for (int nn = 0; nn < 64; ++nn) {
        int n = ntile * 64 + nn;
        float hp = 0.f;
        const float* wr = w_inT + n * N_INP + wv * 64;   // uniform -> s_load
#pragma unroll 8
        for (int c2 = 0; c2 < 64; ++c2)
            hp = fmaf(Li[(wv * 64 + c2) * 64 + lane], wr[c2], hp);
        Lp[wv * 64 + lane] = hp;
        __syncthreads();
        if (wv == 0)
            h1r[(size_t)(s & (H1RING - 1)) * NB + n * 64 + lane] =
                Lp[lane] + Lp[64 + lane] + Lp[128 + lane] + Lp[192 + lane];
        __syncthreads();
    }
}

// ---------------------------------------------------------------------------
// COOPERATIVE span kernel: runs `npairs` step-pairs in ONE launch with
// grid.sync() between pairs, replacing 31 kernel-launch boundaries per span.
// Per-pair arithmetic is VERBATIM the proven round-0 step_pair body (same
// gather order, same shuffle tree, same pointwise) -> bit-exact. Lrec/off/
// delays/p staged ONCE per span; mem/wp hoisted to registers for the span
// (block-private, identical value sequence -> bit-exact).
//
// Visibility: histc writes (wave 0) are released with __threadfence()
// (device scope, cross-XCD) before grid.sync(); readers run strictly after
// the sync. spk is only consumed after this kernel completes. HSLOTS=132
// proves read/write slot-disjointness within a pair (reads <= t0-1, writes
// t0,t0+1), so the only cross-pair hazard is handled by the sync.
__global__ __launch_bounds__(256, 4) void step_span(int t0_base, int npairs,
        const uint2* __restrict__ recs, const int* __restrict__ cnt,
        const int* __restrict__ delays, const float* __restrict__ h1r,
        const float* __restrict__ p,
        float* __restrict__ histc, float* __restrict__ mem,
        float* __restrict__ wp_arr, unsigned long long* __restrict__ spk) {
    cg::grid_group grid = cg::this_grid();
    __shared__ uint2 Lrec[LREC_MAX]; // ~9 KB: this o's record list, d-major, padded
    __shared__ int   off[N_DEL + 1];
    __shared__ float Lg0[4 * 64];    // GEMM partials step t0
    __shared__ float Lg1[4 * 64];    // GEMM partials step t0+1
    int blk  = blockIdx.x;           // o = n
    int tid  = threadIdx.x;
    int lane = tid & 63;             // b
    int wv   = __builtin_amdgcn_readfirstlane(tid >> 6);

    if (tid == 0) {
        int s = 0;
        for (int d = 0; d < N_DEL; ++d) { off[d] = s; s += cnt[blk * N_DEL + d]; }
        off[N_DEL] = s;
    }
    __syncthreads();
    // stage records d-major into LDS once per span; non-temporal (read-once)
    for (int d = 0; d < N_DEL; ++d) {
        const unsigned long long* R =
            (const unsigned long long*)(recs + ((size_t)blk * N_DEL + d) * CAP);
        int base = off[d], n = off[d + 1] - base;
        for (int k = tid; k < n; k += 256) {
            unsigned long long v = __builtin_nontemporal_load(&R[k]);
            Lrec[base + k] = make_uint2((unsigned)v, (unsigned)(v >> 32));
        }
    }
    int d0 = wv * 2, d1 = wv * 2 + 1;
    int dl0 = __builtin_amdgcn_readfirstlane(delays[d0]);
    int dl1 = __builtin_amdgcn_readfirstlane(delays[d1]);
    float pn = p[blk];
    float pd = (pn < 0.f) ? 1.f : 0.f;
    int q  = lane >> 4;              // 0..3 : which record in the quad
    int bq = lane & 15;              // b-quad index
    int i_pw = blk * 64 + lane;
    float m_st = mem[i_pw];          // span-resident state (used by wave 0)
    float w_st = wp_arr[i_pw];
    __syncthreads();

    for (int pi = 0; pi < npairs; ++pi) {
        int t0 = t0_base + pi * 2;
        float4 acc0 = make_float4(0.f, 0.f, 0.f, 0.f);   // step t0
        float4 acc1 = make_float4(0.f, 0.f, 0.f, 0.f);   // step t0+1
#pragma unroll
        for (int seg = 0; seg < 2; ++seg) {
            int d    = seg ? d1 : d0;
            int dl   = seg ? dl1 : dl0;
            int tau0 = t0 - 1 - dl;          // step t0 read
            int tau1 = tau0 + 1;             // step t0+1 read
            int kb = off[d], ke = off[d + 1];   // multiples of 4
            if (tau0 >= 0) {
                // both steps valid: fused dual gather (round-0 8-stride body)
                const float* hb0 = histc + (size_t)(tau0 % HSLOTS) * NB;
                const float* hb1 = histc + (size_t)(tau1 % HSLOTS) * NB;
                int k = kb;
                for (; k + 8 <= ke; k += 8) {
                    uint2 ra = Lrec[k + q];
                    uint2 rb = Lrec[k + 4 + q];
                    float ga = __uint_as_float(ra.x);
                    float gb = __uint_as_float(rb.x);
                    float4 a0 = *((const float4*)(hb0 + ra.y) + bq);
                    float4 a1 = *((const float4*)(hb1 + ra.y) + bq);
                    float4 b0 = *((const float4*)(hb0 + rb.y) + bq);
                    float4 b1 = *((const float4*)(hb1 + rb.y) + bq);
                    acc0.x = fmaf(ga, a0.x, acc0.x); acc0.y = fmaf(ga, a0.y, acc0.y);
                    acc0.z = fmaf(ga, a0.z, acc0.z); acc0.w = fmaf(ga, a0.w, acc0.w);
                    acc1.x = fmaf(ga, a1.x, acc1.x); acc1.y = fmaf(ga, a1.y, acc1.y);
                    acc1.z = fmaf(ga, a1.z, acc1.z); acc1.w = fmaf(ga, a1.w, acc1.w);
                    acc0.x = fmaf(gb, b0.x, acc0.x); acc0.y = fmaf(gb, b0.y, acc0.y);
                    acc0.z = fmaf(gb, b0.z, acc0.z); acc0.w = fmaf(gb, b0.w, acc0.w);
                    acc1.x = fmaf(gb, b1.x, acc1.x); acc1.y = fmaf(gb, b1.y, acc1.y);
                    acc1.z = fmaf(gb, b1.z, acc1.z); acc1.w = fmaf(gb, b1.w, acc1.w);
                }
                if ((ke - kb) & 4) {
                    uint2 r = Lrec[ke - 4 + q];
                    float g = __uint_as_float(r.x);
                    float4 a0 = *((const float4*)(hb0 + r.y) + bq);
                    float4 a1 = *((const float4*)(hb1 + r.y) + bq);
                    acc0.x = fmaf(g, a0.x, acc0.x); acc0.y = fmaf(g, a0.y, acc0.y);
                    acc0.z = fmaf(g, a0.z, acc0.z); acc0.w = fmaf(g, a0.w, acc0.w);
                    acc1.x = fmaf(g, a1.x, acc1.x); acc1.y = fmaf(g, a1.y, acc1.y);
                    acc1.z = fmaf(g, a1.z, acc1.z); acc1.w = fmaf(g, a1.w, acc1.w);
                }
            } else if (tau1 >= 0) {          // only step t0+1 reads (tau0 == -1)
                const float* hb1 = histc + (size_t)(tau1 % HSLOTS) * NB;
                for (int k = kb; k + 4 <= ke; k += 4) {
                    uint2 r = Lrec[k + q];
                    float g = __uint_as_float(r.x);
                    float4 a1 = *((const float4*)(hb1 + r.y) + bq);
                    acc1.x = fmaf(g, a1.x, acc1.x); acc1.y = fmaf(g, a1.y, acc1.y);
                    acc1.z = fmaf(g, a1.z, acc1.z); acc1.w = fmaf(g, a1.w, acc1.w);
                }
            }
        }
        // reduce across q (lane bits 4,5); lanes 0..15 then hold b = bq*4+j
        acc0.x += __shfl_xor(acc0.x, 16); acc0.x += __shfl_xor(acc0.x, 32);
        acc0.y += __shfl_xor(acc0.y, 16); acc0.y += __shfl_xor(acc0.y, 32);
        acc0.z += __shfl_xor(acc0.z, 16); acc0.z += __shfl_xor(acc0.z, 32);
        acc0.w += __shfl_xor(acc0.w, 16); acc0.w += __shfl_xor(acc0.w, 32);
        acc1.x += __shfl_xor(acc1.x, 16); acc1.x += __shfl_xor(acc1.x, 32);
        acc1.y += __shfl_xor(acc1.y, 16); acc1.y += __shfl_xor(acc1.y, 32);
        acc1.z += __shfl_xor(acc1.z, 16); acc1.z += __shfl_xor(acc1.z, 32);
        acc1.w += __shfl_xor(acc1.w, 16); acc1.w += __shfl_xor(acc1.w, 32);
        if (lane < 16) {
            *((float4*)&Lg0[wv * 64 + lane * 4]) = acc0;
            *((float4*)&Lg1[wv * 64 + lane * 4]) = acc1;
        }
        __syncthreads();
        // ---- pointwise(t0) then pointwise(t0+1): intra-block, wave 0.
        // Waves 1-3 wait at grid.sync below, so their next-pair Lg writes
        // cannot race wave 0's reads.
        if (wv == 0) {
#pragma unroll
            for (int sidx = 0; sidx < 2; ++sidx) {
                int s = t0 + sidx;
                const float* Lg = sidx ? Lg1 : Lg0;
                float syn = Lg[lane] + Lg[64 + lane] + Lg[128 + lane] + Lg[192 + lane];
                float h1 = h1r[(size_t)(s & (H1RING - 1)) * NB + i_pw];
                float out = (m_st - 1.f > 0.f) ? 1.f : 0.f;
                w_st = w_st * 0.95f + out * pn * (1.f + pd * w_st);
                histc[(size_t)(s % HSLOTS) * NB + i_pw] = out * (1.f + w_st);
                m_st = 0.9f * m_st + h1 + syn - out;
                unsigned long long mask = __ballot(out > 0.f);
                if (lane == 0) spk[(size_t)s * N_NEUR + blk] = mask;
            }
        }
        // release hist writes device-wide, then barrier before next pair reads
        __threadfence();
        grid.sync();
    }
    if (wv == 0) { mem[i_pw] = m_st; wp_arr[i_pw] = w_st; }
}

// ---------------------------------------------------------------------------
// h2[t][b][o] = sum_n spk_bit(t,n,b) * w_out[n][o]
__global__ __launch_bounds__(256) void h2_gemm(const unsigned long long* __restrict__ spk,
                                               const float* __restrict__ w_out,
                                               float* __restrict__ h2) {
    int t = blockIdx.x;
    int lane = threadIdx.x & 63;     // = b
    int wv   = threadIdx.x >> 6;
    int o0 = wv * 8;
    float acc[8];
#pragma unroll
    for (int j = 0; j < 8; ++j) acc[j] = 0.f;
    for (int n = 0; n < N_NEUR; ++n) {
        unsigned long long mask = spk[(size_t)t * N_NEUR + n];   // uniform
        float s = (float)((mask >> lane) & 1ULL);
        const float* wr = w_out + n * N_OUTC + o0;               // uniform
#pragma unroll
        for (int j = 0; j < 8; ++j) acc[j] = fmaf(s, wr[j], acc[j]);
    }
#pragma unroll
    for (int j = 0; j < 8; ++j)
        h2[((size_t)t * BATCH + lane) * N_OUTC + o0 + j] = acc[j];
}

// out[b][t][o] : leaky-integrator scan over h2
__global__ __launch_bounds__(256) void out_scan(const float* __restrict__ h2,
                                                float* __restrict__ out) {
    int tid = blockIdx.x * 256 + threadIdx.x;   // 2048 = 64b * 32o
    int o = tid & 31;
    int b = tid >> 5;
    float acc = 0.f;
    for (int t = 0; t < T_STEPS; ++t) {
        acc = 0.9f * acc + h2[((size_t)t * BATCH + b) * N_OUTC + o];
        out[((size_t)b * T_STEPS + t) * N_OUTC + o] = acc;
    }
}

// ---------------------------------------------------------------------------
extern "C" void kernel_launch(void* const* d_in, const int* in_sizes, int n_in,
                              void* d_out, int out_size, void* d_ws, size_t ws_size,
                              hipStream_t stream) {
    (void)in_sizes; (void)n_in; (void)out_size; (void)ws_size;
    const float* inputs = (const float*)d_in[0];
    const float* w      = (const float*)d_in[1];
    const float* w_in   = (const float*)d_in[2];
    const float* w_out  = (const float*)d_in[3];
    const float* signs  = (const float*)d_in[4];
    const float* p      = (const float*)d_in[5];
    const float* dmap   = (const float*)d_in[6];
    const int*   delays = (const int*)d_in[7];
    float* out = (float*)d_out;

    // workspace layout (~106 MiB total, under proven 120.6 MiB)
    float* ws    = (float*)d_ws;
    float* inpT  = ws;                                    //  8,192,000 f
    float* w_inT = inpT + (size_t)T_STEPS * N_INP * 64;   //    262,144 f
    float* histc = w_inT + (size_t)N_NEUR * N_INP;        //  8,650,752 f
    float* h1r   = histc + (size_t)HSLOTS * NB;           //  4,194,304 f
    float* mem   = h1r + (size_t)H1RING * NB;             //     65,536 f
    float* wp    = mem + NB;                              //     65,536 f
    float* h2    = wp + NB;                               //  1,024,000 f
    int*   cnt   = (int*)(h2 + (size_t)T_STEPS * BATCH * N_OUTC);  // 8192 i
    uint2* recs  = (uint2*)(cnt + N_NEUR * N_DEL);        //  2,097,152 uint2
    unsigned long long* spk =
        (unsigned long long*)(recs + (size_t)N_NEUR * N_DEL * CAP); // 512,000 ull

    hipMemsetAsync(histc, 0, sizeof(float) * (size_t)HSLOTS * NB, stream);
    hipMemsetAsync(mem, 0, sizeof(float) * (size_t)2 * NB, stream);  // mem+wp adjacent

    transpose_inp<<<T_STEPS, 256, 0, stream>>>(inputs, inpT);
    transpose_win<<<(N_NEUR * N_INP) / 256, 256, 0, stream>>>(w_in, w_inT);
    build_csr<<<16, 64, 0, stream>>>(w, signs, dmap, recs, cnt);

    for (int t0 = 0; t0 < T_STEPS; t0 += H1RING) {
        int ns = T_STEPS - t0; if (ns > H1RING) ns = H1RING;
        h1_chunk<<<dim3(ns, 16), 256, 0, stream>>>(t0, inpT, w_inT, h1r);
        int t0v = t0, npv = ns / 2;
        void* kargs[] = { &t0v, &npv, (void*)&recs, (void*)&cnt, (void*)&delays,
                          (void*)&h1r, (void*)&p, (void*)&histc, (void*)&mem,
                          (void*)&wp, (void*)&spk };
        hipLaunchCooperativeKernel((const void*)step_span, dim3(N_NEUR), dim3(256),
                                   kargs, 0, stream);
    }

    h2_gemm<<<T_STEPS, 256, 0, stream>>>(spk, w_out, h2);
    out_scan<<<8, 256, 0, stream>>>(h2, out);
}

// Round 5
// 8658.746 us; speedup vs baseline: 6.8803x; 6.8803x over previous
//
#include <hip/hip_runtime.h>
#include <stdint.h>

#define N_NEUR  1024
#define N_INP   256
#define N_OUTC  32
#define T_STEPS 500
#define BATCH   64
#define N_DEL   8
#define NB      (N_NEUR*BATCH)     // 65536, layout [n][b], b fastest
#define HSLOTS  132                // ring: live window is 131 steps (writes t0,t0+1;
                                   // reads t0-129..t0-1) -> 132 proves no aliasing.
#define CAP     256                // per-(o,d) record capacity (mean 128, 12 sigma)
#define H1RING  64                 // h1 ring depth (steps), power of 2

// ---------------------------------------------------------------------------
// inpT[t][c][b] = inputs[b][t][c]
__global__ __launch_bounds__(256) void transpose_inp(const float* __restrict__ inp,
                                                     float* __restrict__ inpT) {
    __shared__ float L[N_INP * 64];
    int t = blockIdx.x;
    int tid = threadIdx.x;                   // = c
    for (int b = 0; b < 64; ++b) {
        float v = inp[((size_t)b * T_STEPS + t) * N_INP + tid];
        L[tid * 64 + (b ^ (tid & 63))] = v;
    }
    __syncthreads();
    int lane = tid & 63;
    int wv   = tid >> 6;
    for (int cc = 0; cc < 64; ++cc) {
        int c = cc * 4 + wv;
        inpT[((size_t)t * N_INP + c) * 64 + lane] = L[c * 64 + (lane ^ (c & 63))];
    }
}

// w_inT[n][c] = w_in[c][n]
__global__ __launch_bounds__(256) void transpose_win(const float* __restrict__ w_in,
                                                     float* __restrict__ w_inT) {
    int i = blockIdx.x * 256 + threadIdx.x;  // 262144
    int n = i >> 8, c = i & 255;
    w_inT[i] = w_in[(size_t)c * N_NEUR + n];
}

// ---------------------------------------------------------------------------
// CSR build: for each (o,d), list of {G = sign[e]*|w[e][o]|, e*64} where
// dmap[d][e][o] == 1. Padded to a multiple of 4 with zero-records (G=0 -> inert).
// Records e-ASCENDING within each segment (load-bearing for bit-exact order).
// Round-5: parallelized over (o,d) -> grid(16,8), 8x thread count, same
// per-segment scan (bit-exact contents).
__global__ __launch_bounds__(64) void build_csr(const float* __restrict__ w,
                                                const float* __restrict__ signs,
                                                const float* __restrict__ dmap,
                                                uint2* __restrict__ recs,
                                                int* __restrict__ cnt) {
    int o = blockIdx.x * 64 + threadIdx.x;   // 16 blocks x 64 lanes
    int d = blockIdx.y;                      // 8
    int c = 0;
    uint2* seg = recs + ((size_t)o * N_DEL + d) * CAP;
    for (int e = 0; e < N_NEUR; ++e) {
        float m = dmap[((size_t)d * N_NEUR + e) * N_NEUR + o];  // coalesced over o
        if (m != 0.f) {
            float G = signs[e] * fabsf(w[(size_t)e * N_NEUR + o]);
            if (c < CAP) seg[c] = make_uint2(__float_as_uint(G), (unsigned)(e * 64));
            ++c;
        }
    }
    if (c > CAP) c = CAP;
    int c4 = (c + 3) & ~3;                // pad to multiple of 4
    for (; c < c4; ++c) seg[c] = make_uint2(0u, 0u);
    cnt[o * N_DEL + d] = c4;
}

// ---------------------------------------------------------------------------
// h1 ring precompute, 64 steps per launch (bit-exact, unchanged).
__global__ __launch_bounds__(256) void h1_chunk(int t0,
        const float* __restrict__ inpT, const float* __restrict__ w_inT,
        float* __restrict__ h1r) {
    __shared__ float Li[N_INP * 64];   // 64 KB
    __shared__ float Lp[4 * 64];
    int s     = t0 + blockIdx.x;
    int ntile = blockIdx.y;            // 16 tiles x 64 n
    int tid   = threadIdx.x;
    int lane  = tid & 63;
    int wv    = tid >> 6;
    const float4* src = (const float4*)(inpT + (size_t)s * (N_INP * 64));
    float4* dst = (float4*)Li;
    for (int k = tid; k < (N_INP * 64) / 4; k += 256) dst[k] = src[k];
    __syncthreads();
    for (int nn = 0; nn < 64; ++nn) {
        int n = ntile * 64 + nn;
        float hp = 0.f;
        const float* wr = w_inT + n * N_INP + wv * 64;   // uniform -> s_load
#pragma unroll 8
        for (int c2 = 0; c2 < 64; ++c2)
            hp = fmaf(Li[(wv * 64 + c2) * 64 + lane], wr[c2], hp);
        Lp[wv * 64 + lane] = hp;
        __syncthreads();
        if (wv == 0)
            h1r[(size_t)(s & (H1RING - 1)) * NB + n * 64 + lane] =
                Lp[lane] + Lp[64 + lane] + Lp[128 + lane] + Lp[192 + lane];
        __syncthreads();
    }
}

// ---------------------------------------------------------------------------
// Round-5 split: GATHER kernel. One wave = one (o, d-pair, step) chain.
// 2048 blocks x 4 waves -> 8 blocks/CU x 4 waves = 32 waves/CU (100% occ,
// vs 47% in the fused step_pair) -> 2x outstanding gather lines.
// Bit-exact: per-lane record chain (ascending k, = q mod 4 within segment,
// d_even then d_odd serial in ONE acc chain) and the shfl_xor 16/32 q-reduce
// are verbatim round-0; removing the other step's interleaved fmas does not
// change this chain's values. Partials P[step][o][dp][b] are summed by
// step_point in the exact old wv0+wv1+wv2+wv3 order.
// All hist reads are pre-launch (steps <= t0-1): both steps' gathers are
// fully parallel; only the pointwise is serial -> it moves to step_point.
__global__ __launch_bounds__(256) void step_gather(int t0,
        const uint2* __restrict__ recs, const int* __restrict__ cnt,
        const int* __restrict__ delays, const float* __restrict__ histc,
        float* __restrict__ P) {
    __shared__ uint2 Lrec[4 * CAP];  // 8 KB: 4 segments (this o, d-half), padded
    __shared__ int   off[5];
    int blk  = blockIdx.x;           // 2048: o = blk>>1, h = blk&1 (d in [4h,4h+4))
    int o    = blk >> 1;
    int h    = blk & 1;
    int tid  = threadIdx.x;
    int lane = tid & 63;
    int wv   = __builtin_amdgcn_readfirstlane(tid >> 6);

    if (tid == 0) {
        int s = 0;
        for (int j = 0; j < 4; ++j) { off[j] = s; s += cnt[o * N_DEL + 4 * h + j]; }
        off[4] = s;
    }
    __syncthreads();
    // stage this (o, d-half)'s records into LDS; non-temporal (read-once)
    for (int j = 0; j < 4; ++j) {
        const unsigned long long* R =
            (const unsigned long long*)(recs + ((size_t)o * N_DEL + 4 * h + j) * CAP);
        int base = off[j], n = off[j + 1] - base;
        for (int k = tid; k < n; k += 256) {
            unsigned long long v = __builtin_nontemporal_load(&R[k]);
            Lrec[base + k] = make_uint2((unsigned)v, (unsigned)(v >> 32));
        }
    }
    int dpl  = wv >> 1;              // local d-pair 0/1; global dp = 2h + dpl
    int sidx = wv & 1;               // step within the pair
    int j0 = dpl * 2, j1 = j0 + 1;   // segment indices within block
    int dl0 = __builtin_amdgcn_readfirstlane(delays[4 * h + j0]);
    int dl1 = __builtin_amdgcn_readfirstlane(delays[4 * h + j1]);
    int q  = lane >> 4;              // 0..3 : which record in the quad
    int bq = lane & 15;              // b-quad index
    __syncthreads();

    float4 acc = make_float4(0.f, 0.f, 0.f, 0.f);
#pragma unroll
    for (int seg = 0; seg < 2; ++seg) {
        int j   = seg ? j1 : j0;
        int dl  = seg ? dl1 : dl0;
        int tau = t0 + sidx - 1 - dl;    // this step's read slot (absolute)
        if (tau >= 0) {
            const float* hb = histc + (size_t)(tau % HSLOTS) * NB;
            int kb = off[j], ke = off[j + 1];
            int k = kb;
            for (; k + 8 <= ke; k += 8) {
                uint2 ra = Lrec[k + q];
                uint2 rb = Lrec[k + 4 + q];
                float ga = __uint_as_float(ra.x);
                float gb = __uint_as_float(rb.x);
                float4 a = *((const float4*)(hb + ra.y) + bq);
                float4 b = *((const float4*)(hb + rb.y) + bq);
                acc.x = fmaf(ga, a.x, acc.x); acc.y = fmaf(ga, a.y, acc.y);
                acc.z = fmaf(ga, a.z, acc.z); acc.w = fmaf(ga, a.w, acc.w);
                acc.x = fmaf(gb, b.x, acc.x); acc.y = fmaf(gb, b.y, acc.y);
                acc.z = fmaf(gb, b.z, acc.z); acc.w = fmaf(gb, b.w, acc.w);
            }
            if ((ke - kb) & 4) {
                uint2 r = Lrec[ke - 4 + q];
                float g = __uint_as_float(r.x);
                float4 a = *((const float4*)(hb + r.y) + bq);
                acc.x = fmaf(g, a.x, acc.x); acc.y = fmaf(g, a.y, acc.y);
                acc.z = fmaf(g, a.z, acc.z); acc.w = fmaf(g, a.w, acc.w);
            }
        }
    }
    // reduce across q (lane bits 4,5); lanes 0..15 then hold b = lane*4..+3
    acc.x += __shfl_xor(acc.x, 16); acc.x += __shfl_xor(acc.x, 32);
    acc.y += __shfl_xor(acc.y, 16); acc.y += __shfl_xor(acc.y, 32);
    acc.z += __shfl_xor(acc.z, 16); acc.z += __shfl_xor(acc.z, 32);
    acc.w += __shfl_xor(acc.w, 16); acc.w += __shfl_xor(acc.w, 32);
    if (lane < 16) {
        int dpg = 2 * h + dpl;       // global d-pair 0..3 (== old wave index wv)
        *((float4*)(P + (((size_t)sidx * N_NEUR + o) * 4 + dpg) * 64 + lane * 4)) = acc;
    }
}

// ---------------------------------------------------------------------------
// Round-5 split: POINTWISE kernel. One wave = one o (lane = b). Sums the 4
// d-pair partials in the exact old wv0+wv1+wv2+wv3 order, then runs the two
// serial pointwise steps (verbatim round-0 formulas) -> bit-exact.
__global__ __launch_bounds__(256) void step_point(int t0,
        const float* __restrict__ P, const float* __restrict__ h1r,
        const float* __restrict__ p,
        float* __restrict__ histc, float* __restrict__ mem,
        float* __restrict__ wp_arr, unsigned long long* __restrict__ spk) {
    int i    = blockIdx.x * 256 + threadIdx.x;   // 65536 = 1024 o * 64 b
    int o    = i >> 6;
    int lane = i & 63;
    float pn = p[o];
    float pd = (pn < 0.f) ? 1.f : 0.f;
    float m = mem[i];
    float w = wp_arr[i];
#pragma unroll
    for (int sidx = 0; sidx < 2; ++sidx) {
        int s = t0 + sidx;
        const float* Pp = P + ((size_t)sidx * N_NEUR + o) * 4 * 64 + lane;
        float syn = Pp[0] + Pp[64] + Pp[128] + Pp[192];
        float h1 = h1r[(size_t)(s & (H1RING - 1)) * NB + i];
        float out = (m - 1.f > 0.f) ? 1.f : 0.f;
        w = w * 0.95f + out * pn * (1.f + pd * w);
        histc[(size_t)(s % HSLOTS) * NB + i] = out * (1.f + w);
        m = 0.9f * m + h1 + syn - out;
        unsigned long long mask = __ballot(out > 0.f);
        if (lane == 0) spk[(size_t)s * N_NEUR + o] = mask;
    }
    mem[i] = m;
    wp_arr[i] = w;
}

// ---------------------------------------------------------------------------
// h2[t][b][o] = sum_n spk_bit(t,n,b) * w_out[n][o]
__global__ __launch_bounds__(256) void h2_gemm(const unsigned long long* __restrict__ spk,
                                               const float* __restrict__ w_out,
                                               float* __restrict__ h2) {
    int t = blockIdx.x;
    int lane = threadIdx.x & 63;     // = b
    int wv   = threadIdx.x >> 6;
    int o0 = wv * 8;
    float acc[8];
#pragma unroll
    for (int j = 0; j < 8; ++j) acc[j] = 0.f;
    for (int n = 0; n < N_NEUR; ++n) {
        unsigned long long mask = spk[(size_t)t * N_NEUR + n];   // uniform
        float s = (float)((mask >> lane) & 1ULL);
        const float* wr = w_out + n * N_OUTC + o0;               // uniform
#pragma unroll
        for (int j = 0; j < 8; ++j) acc[j] = fmaf(s, wr[j], acc[j]);
    }
#pragma unroll
    for (int j = 0; j < 8; ++j)
        h2[((size_t)t * BATCH + lane) * N_OUTC + o0 + j] = acc[j];
}

// out[b][t][o] : leaky-integrator scan over h2
__global__ __launch_bounds__(256) void out_scan(const float* __restrict__ h2,
                                                float* __restrict__ out) {
    int tid = blockIdx.x * 256 + threadIdx.x;   // 2048 = 64b * 32o
    int o = tid & 31;
    int b = tid >> 5;
    float acc = 0.f;
    for (int t = 0; t < T_STEPS; ++t) {
        acc = 0.9f * acc + h2[((size_t)t * BATCH + b) * N_OUTC + o];
        out[((size_t)b * T_STEPS + t) * N_OUTC + o] = acc;
    }
}

// ---------------------------------------------------------------------------
extern "C" void kernel_launch(void* const* d_in, const int* in_sizes, int n_in,
                              void* d_out, int out_size, void* d_ws, size_t ws_size,
                              hipStream_t stream) {
    (void)in_sizes; (void)n_in; (void)out_size; (void)ws_size;
    const float* inputs = (const float*)d_in[0];
    const float* w      = (const float*)d_in[1];
    const float* w_in   = (const float*)d_in[2];
    const float* w_out  = (const float*)d_in[3];
    const float* signs  = (const float*)d_in[4];
    const float* p      = (const float*)d_in[5];
    const float* dmap   = (const float*)d_in[6];
    const int*   delays = (const int*)d_in[7];
    float* out = (float*)d_out;

    // workspace layout (~108 MiB total, under proven 120.6 MiB)
    float* ws    = (float*)d_ws;
    float* inpT  = ws;                                    //  8,192,000 f
    float* w_inT = inpT + (size_t)T_STEPS * N_INP * 64;   //    262,144 f
    float* histc = w_inT + (size_t)N_NEUR * N_INP;        //  8,650,752 f
    float* h1r   = histc + (size_t)HSLOTS * NB;           //  4,194,304 f
    float* mem   = h1r + (size_t)H1RING * NB;             //     65,536 f
    float* wp    = mem + NB;                              //     65,536 f
    float* h2    = wp + NB;                               //  1,024,000 f
    int*   cnt   = (int*)(h2 + (size_t)T_STEPS * BATCH * N_OUTC);  // 8192 i
    uint2* recs  = (uint2*)(cnt + N_NEUR * N_DEL);        //  2,097,152 uint2
    unsigned long long* spk =
        (unsigned long long*)(recs + (size_t)N_NEUR * N_DEL * CAP); // 512,000 ull
    float* P     = (float*)(spk + (size_t)T_STEPS * N_NEUR);        //   524,288 f

    hipMemsetAsync(histc, 0, sizeof(float) * (size_t)HSLOTS * NB, stream);
    hipMemsetAsync(mem, 0, sizeof(float) * (size_t)2 * NB, stream);  // mem+wp adjacent

    transpose_inp<<<T_STEPS, 256, 0, stream>>>(inputs, inpT);
    transpose_win<<<(N_NEUR * N_INP) / 256, 256, 0, stream>>>(w_in, w_inT);
    build_csr<<<dim3(16, 8), 64, 0, stream>>>(w, signs, dmap, recs, cnt);

    for (int t0 = 0; t0 < T_STEPS; t0 += 2) {
        if ((t0 & (H1RING - 1)) == 0) {
            int ns = T_STEPS - t0; if (ns > H1RING) ns = H1RING;
            h1_chunk<<<dim3(ns, 16), 256, 0, stream>>>(t0, inpT, w_inT, h1r);
        }
        step_gather<<<2 * N_NEUR, 256, 0, stream>>>(t0, recs, cnt, delays, histc, P);
        step_point<<<NB / 256, 256, 0, stream>>>(t0, P, h1r, p, histc, mem, wp, spk);
    }

    h2_gemm<<<T_STEPS, 256, 0, stream>>>(spk, w_out, h2);
    out_scan<<<8, 256, 0, stream>>>(h2, out);
}

// Round 6
// 8578.115 us; speedup vs baseline: 6.9450x; 1.0094x over previous
//
#include <hip/hip_runtime.h>
#include <stdint.h>

#define N_NEUR  1024
#define N_INP   256
#define N_OUTC  32
#define T_STEPS 500
#define BATCH   64
#define N_DEL   8
#define NB      (N_NEUR*BATCH)     // 65536, layout [n][b], b fastest
#define HSLOTS  132                // ring: live window is 131 steps (writes t0,t0+1;
                                   // reads t0-129..t0-1) -> 132 proves no aliasing.
#define CAP     256                // per-(o,d) record capacity (mean 128, 12 sigma)
#define H1RING  64                 // h1 ring depth (steps), power of 2
#define LREC_MAX 1152              // >= 1024 + 8*3 padding

// ---------------------------------------------------------------------------
// inpT[t][c][b] = inputs[b][t][c]
__global__ __launch_bounds__(256) void transpose_inp(const float* __restrict__ inp,
                                                     float* __restrict__ inpT) {
    __shared__ float L[N_INP * 64];
    int t = blockIdx.x;
    int tid = threadIdx.x;                   // = c
    for (int b = 0; b < 64; ++b) {
        float v = inp[((size_t)b * T_STEPS + t) * N_INP + tid];
        L[tid * 64 + (b ^ (tid & 63))] = v;
    }
    __syncthreads();
    int lane = tid & 63;
    int wv   = tid >> 6;
    for (int cc = 0; cc < 64; ++cc) {
        int c = cc * 4 + wv;
        inpT[((size_t)t * N_INP + c) * 64 + lane] = L[c * 64 + (lane ^ (c & 63))];
    }
}

// w_inT[n][c] = w_in[c][n]
__global__ __launch_bounds__(256) void transpose_win(const float* __restrict__ w_in,
                                                     float* __restrict__ w_inT) {
    int i = blockIdx.x * 256 + threadIdx.x;  // 262144
    int n = i >> 8, c = i & 255;
    w_inT[i] = w_in[(size_t)c * N_NEUR + n];
}

// ---------------------------------------------------------------------------
// CSR build: for each (o,d), list of {G = sign[e]*|w[e][o]|, e*64} where
// dmap[d][e][o] == 1. Padded to a multiple of 4 with zero-records (G=0 -> inert).
// Records e-ASCENDING within each segment (load-bearing for bit-exact order).
// Parallel over (o,d): grid(16,8) (round-5, confirmed).
__global__ __launch_bounds__(64) void build_csr(const float* __restrict__ w,
                                                const float* __restrict__ signs,
                                                const float* __restrict__ dmap,
                                                uint2* __restrict__ recs,
                                                int* __restrict__ cnt) {
    int o = blockIdx.x * 64 + threadIdx.x;   // 16 blocks x 64 lanes
    int d = blockIdx.y;                      // 8
    int c = 0;
    uint2* seg = recs + ((size_t)o * N_DEL + d) * CAP;
    for (int e = 0; e < N_NEUR; ++e) {
        float m = dmap[((size_t)d * N_NEUR + e) * N_NEUR + o];  // coalesced over o
        if (m != 0.f) {
            float G = signs[e] * fabsf(w[(size_t)e * N_NEUR + o]);
            if (c < CAP) seg[c] = make_uint2(__float_as_uint(G), (unsigned)(e * 64));
            ++c;
        }
    }
    if (c > CAP) c = CAP;
    int c4 = (c + 3) & ~3;                // pad to multiple of 4
    for (; c < c4; ++c) seg[c] = make_uint2(0u, 0u);
    cnt[o * N_DEL + d] = c4;
}

// ---------------------------------------------------------------------------
// h1 ring precompute, 64 steps per launch (bit-exact, unchanged).
__global__ __launch_bounds__(256) void h1_chunk(int t0,
        const float* __restrict__ inpT, const float* __restrict__ w_inT,
        float* __restrict__ h1r) {
    __shared__ float Li[N_INP * 64];   // 64 KB
    __shared__ float Lp[4 * 64];
    int s     = t0 + blockIdx.x;
    int ntile = blockIdx.y;            // 16 tiles x 64 n
    int tid   = threadIdx.x;
    int lane  = tid & 63;
    int wv    = tid >> 6;
    const float4* src = (const float4*)(inpT + (size_t)s * (N_INP * 64));
    float4* dst = (float4*)Li;
    for (int k = tid; k < (N_INP * 64) / 4; k += 256) dst[k] = src[k];
    __syncthreads();
    for (int nn = 0; nn < 64; ++nn) {
        int n = ntile * 64 + nn;
        float hp = 0.f;
        const float* wr = w_inT + n * N_INP + wv * 64;   // uniform -> s_load
#pragma unroll 8
        for (int c2 = 0; c2 < 64; ++c2)
            hp = fmaf(Li[(wv * 64 + c2) * 64 + lane], wr[c2], hp);
        Lp[wv * 64 + lane] = hp;
        __syncthreads();
        if (wv == 0)
            h1r[(size_t)(s & (H1RING - 1)) * NB + n * 64 + lane] =
                Lp[lane] + Lp[64 + lane] + Lp[128 + lane] + Lp[192 + lane];
        __syncthreads();
    }
}

// ---------------------------------------------------------------------------
// Round-6 fused pair kernel: 1024 blocks x 512 threads (8 waves). Wave =
// one (d-pair, step) chain -- EXACTLY round-5's step_gather chains (dp =
// wv>>1, sidx = wv&1), so 32 waves/CU occupancy is preserved, but all 8
// partials for this o now live in one block: the pointwise tail runs
// in-block on wave 0, deleting the step_point launch and the P buffer
// round-trip. Partials summed in the same dp0+dp1+dp2+dp3 order as
// round-5's step_point -> bit-exact. Tail inputs (mem/wp/h1r) prefetched
// to registers before the gather loop (block-private -> bit-exact).
// All hist reads are steps <= t0-1 (pre-launch); writes are t0,t0+1;
// HSLOTS=132 proves slot-disjointness.
__global__ __launch_bounds__(512, 8) void step_fused(int t0,
        const uint2* __restrict__ recs, const int* __restrict__ cnt,
        const int* __restrict__ delays, const float* __restrict__ h1r,
        const float* __restrict__ p,
        float* __restrict__ histc, float* __restrict__ mem,
        float* __restrict__ wp_arr, unsigned long long* __restrict__ spk) {
    __shared__ uint2 Lrec[LREC_MAX]; // ~9 KB: this o's record list, d-major, padded
    __shared__ int   off[N_DEL + 1];
    __shared__ float Lg0[4 * 64];    // partials step t0, [dp][b]
    __shared__ float Lg1[4 * 64];    // partials step t0+1
    int o    = blockIdx.x;
    int tid  = threadIdx.x;
    int lane = tid & 63;             // b
    int wv   = __builtin_amdgcn_readfirstlane(tid >> 6);   // 0..7

    if (tid == 0) {
        int s = 0;
        for (int d = 0; d < N_DEL; ++d) { off[d] = s; s += cnt[o * N_DEL + d]; }
        off[N_DEL] = s;
    }
    __syncthreads();
    // stage records d-major into LDS (512 threads); non-temporal (read-once)
    for (int d = 0; d < N_DEL; ++d) {
        const unsigned long long* R =
            (const unsigned long long*)(recs + ((size_t)o * N_DEL + d) * CAP);
        int base = off[d], n = off[d + 1] - base;
        for (int k = tid; k < n; k += 512) {
            unsigned long long v = __builtin_nontemporal_load(&R[k]);
            Lrec[base + k] = make_uint2((unsigned)v, (unsigned)(v >> 32));
        }
    }
    int dp   = wv >> 1;              // d-pair 0..3 (== round-0 wave index)
    int sidx = wv & 1;               // step within the pair
    int j0 = dp * 2, j1 = j0 + 1;
    int dl0 = __builtin_amdgcn_readfirstlane(delays[j0]);
    int dl1 = __builtin_amdgcn_readfirstlane(delays[j1]);
    float pn = p[o];
    float pd = (pn < 0.f) ? 1.f : 0.f;
    int q  = lane >> 4;              // 0..3 : which record in the quad
    int bq = lane & 15;              // b-quad index

    // prefetch pointwise-tail inputs (block-private; latency hides under loop)
    int i_pw = o * 64 + lane;
    float m_pre   = mem[i_pw];
    float w_pre   = wp_arr[i_pw];
    float h1_pre0 = h1r[(size_t)(t0 & (H1RING - 1)) * NB + i_pw];
    float h1_pre1 = h1r[(size_t)((t0 + 1) & (H1RING - 1)) * NB + i_pw];
    __syncthreads();

    float4 acc = make_float4(0.f, 0.f, 0.f, 0.f);
#pragma unroll
    for (int seg = 0; seg < 2; ++seg) {
        int j   = seg ? j1 : j0;
        int dl  = seg ? dl1 : dl0;
        int tau = t0 + sidx - 1 - dl;    // this step's read slot (absolute)
        if (tau >= 0) {
            const float* hb = histc + (size_t)(tau % HSLOTS) * NB;
            int kb = off[j], ke = off[j + 1];
            int k = kb;
            for (; k + 8 <= ke; k += 8) {
                uint2 ra = Lrec[k + q];
                uint2 rb = Lrec[k + 4 + q];
                float ga = __uint_as_float(ra.x);
                float gb = __uint_as_float(rb.x);
                float4 a = *((const float4*)(hb + ra.y) + bq);
                float4 b = *((const float4*)(hb + rb.y) + bq);
                acc.x = fmaf(ga, a.x, acc.x); acc.y = fmaf(ga, a.y, acc.y);
                acc.z = fmaf(ga, a.z, acc.z); acc.w = fmaf(ga, a.w, acc.w);
                acc.x = fmaf(gb, b.x, acc.x); acc.y = fmaf(gb, b.y, acc.y);
                acc.z = fmaf(gb, b.z, acc.z); acc.w = fmaf(gb, b.w, acc.w);
            }
            if ((ke - kb) & 4) {
                uint2 r = Lrec[ke - 4 + q];
                float g = __uint_as_float(r.x);
                float4 a = *((const float4*)(hb + r.y) + bq);
                acc.x = fmaf(g, a.x, acc.x); acc.y = fmaf(g, a.y, acc.y);
                acc.z = fmaf(g, a.z, acc.z); acc.w = fmaf(g, a.w, acc.w);
            }
        }
    }
    // reduce across q (lane bits 4,5); lanes 0..15 then hold b = lane*4..+3
    acc.x += __shfl_xor(acc.x, 16); acc.x += __shfl_xor(acc.x, 32);
    acc.y += __shfl_xor(acc.y, 16); acc.y += __shfl_xor(acc.y, 32);
    acc.z += __shfl_xor(acc.z, 16); acc.z += __shfl_xor(acc.z, 32);
    acc.w += __shfl_xor(acc.w, 16); acc.w += __shfl_xor(acc.w, 32);
    if (lane < 16) {
        float* Lg = sidx ? Lg1 : Lg0;
        *((float4*)&Lg[dp * 64 + lane * 4]) = acc;
    }
    __syncthreads();
    // ---- pointwise(t0) then pointwise(t0+1): wave 0 (verbatim formulas)
    if (wv == 0) {
        float m = m_pre;
        float w = w_pre;
#pragma unroll
        for (int sx = 0; sx < 2; ++sx) {
            int s = t0 + sx;
            const float* Lg = sx ? Lg1 : Lg0;
            float syn = Lg[lane] + Lg[64 + lane] + Lg[128 + lane] + Lg[192 + lane];
            float h1 = sx ? h1_pre1 : h1_pre0;
            float out = (m - 1.f > 0.f) ? 1.f : 0.f;
            w = w * 0.95f + out * pn * (1.f + pd * w);
            histc[(size_t)(s % HSLOTS) * NB + i_pw] = out * (1.f + w);
            m = 0.9f * m + h1 + syn - out;
            unsigned long long mask = __ballot(out > 0.f);
            if (lane == 0) spk[(size_t)s * N_NEUR + o] = mask;
        }
        mem[i_pw] = m;
        wp_arr[i_pw] = w;
    }
}

// ---------------------------------------------------------------------------
// h2[t][b][o] = sum_n spk_bit(t,n,b) * w_out[n][o]
__global__ __launch_bounds__(256) void h2_gemm(const unsigned long long* __restrict__ spk,
                                               const float* __restrict__ w_out,
                                               float* __restrict__ h2) {
    int t = blockIdx.x;
    int lane = threadIdx.x & 63;     // = b
    int wv   = threadIdx.x >> 6;
    int o0 = wv * 8;
    float acc[8];
#pragma unroll
    for (int j = 0; j < 8; ++j) acc[j] = 0.f;
    for (int n = 0; n < N_NEUR; ++n) {
        unsigned long long mask = spk[(size_t)t * N_NEUR + n];   // uniform
        float s = (float)((mask >> lane) & 1ULL);
        const float* wr = w_out + n * N_OUTC + o0;               // uniform
#pragma unroll
        for (int j = 0; j < 8; ++j) acc[j] = fmaf(s, wr[j], acc[j]);
    }
#pragma unroll
    for (int j = 0; j < 8; ++j)
        h2[((size_t)t * BATCH + lane) * N_OUTC + o0 + j] = acc[j];
}

// out[b][t][o] : leaky-integrator scan over h2
__global__ __launch_bounds__(256) void out_scan(const float* __restrict__ h2,
                                                float* __restrict__ out) {
    int tid = blockIdx.x * 256 + threadIdx.x;   // 2048 = 64b * 32o
    int o = tid & 31;
    int b = tid >> 5;
    float acc = 0.f;
    for (int t = 0; t < T_STEPS; ++t) {
        acc = 0.9f * acc + h2[((size_t)t * BATCH + b) * N_OUTC + o];
        out[((size_t)b * T_STEPS + t) * N_OUTC + o] = acc;
    }
}

// ---------------------------------------------------------------------------
extern "C" void kernel_launch(void* const* d_in, const int* in_sizes, int n_in,
                              void* d_out, int out_size, void* d_ws, size_t ws_size,
                              hipStream_t stream) {
    (void)in_sizes; (void)n_in; (void)out_size; (void)ws_size;
    const float* inputs = (const float*)d_in[0];
    const float* w      = (const float*)d_in[1];
    const float* w_in   = (const float*)d_in[2];
    const float* w_out  = (const float*)d_in[3];
    const float* signs  = (const float*)d_in[4];
    const float* p      = (const float*)d_in[5];
    const float* dmap   = (const float*)d_in[6];
    const int*   delays = (const int*)d_in[7];
    float* out = (float*)d_out;

    // workspace layout (~106 MiB total, under proven 120.6 MiB)
    float* ws    = (float*)d_ws;
    float* inpT  = ws;                                    //  8,192,000 f
    float* w_inT = inpT + (size_t)T_STEPS * N_INP * 64;   //    262,144 f
    float* histc = w_inT + (size_t)N_NEUR * N_INP;        //  8,650,752 f
    float* h1r   = histc + (size_t)HSLOTS * NB;           //  4,194,304 f
    float* mem   = h1r + (size_t)H1RING * NB;             //     65,536 f
    float* wp    = mem + NB;                              //     65,536 f
    float* h2    = wp + NB;                               //  1,024,000 f
    int*   cnt   = (int*)(h2 + (size_t)T_STEPS * BATCH * N_OUTC);  // 8192 i
    uint2* recs  = (uint2*)(cnt + N_NEUR * N_DEL);        //  2,097,152 uint2
    unsigned long long* spk =
        (unsigned long long*)(recs + (size_t)N_NEUR * N_DEL * CAP); // 512,000 ull

    hipMemsetAsync(histc, 0, sizeof(float) * (size_t)HSLOTS * NB, stream);
    hipMemsetAsync(mem, 0, sizeof(float) * (size_t)2 * NB, stream);  // mem+wp adjacent

    transpose_inp<<<T_STEPS, 256, 0, stream>>>(inputs, inpT);
    transpose_win<<<(N_NEUR * N_INP) / 256, 256, 0, stream>>>(w_in, w_inT);
    build_csr<<<dim3(16, 8), 64, 0, stream>>>(w, signs, dmap, recs, cnt);

    for (int t0 = 0; t0 < T_STEPS; t0 += 2) {
        if ((t0 & (H1RING - 1)) == 0) {
            int ns = T_STEPS - t0; if (ns > H1RING) ns = H1RING;
            h1_chunk<<<dim3(ns, 16), 256, 0, stream>>>(t0, inpT, w_inT, h1r);
        }
        step_fused<<<N_NEUR, 512, 0, stream>>>(t0, recs, cnt, delays, h1r, p,
                                               histc, mem, wp, spk);
    }

    h2_gemm<<<T_STEPS, 256, 0, stream>>>(spk, w_out, h2);
    out_scan<<<8, 256, 0, stream>>>(h2, out);
}